// Round 1
// baseline (324.670 us; speedup 1.0000x reference)
//
#include <hip/hip_runtime.h>

// ---------- helpers ----------
typedef __attribute__((ext_vector_type(8))) short short8;
typedef __attribute__((ext_vector_type(4))) float floatx4;

__device__ __forceinline__ unsigned short f2bf(float f) {
    unsigned int u = __builtin_bit_cast(unsigned int, f);
    u += 0x7fffu + ((u >> 16) & 1u);   // round-to-nearest-even (inputs are finite/normal)
    return (unsigned short)(u >> 16);
}

__device__ __forceinline__ void async16(unsigned short* lds, const unsigned short* g) {
    __builtin_amdgcn_global_load_lds(
        (__attribute__((address_space(1))) void*)(g),
        (__attribute__((address_space(3))) void*)(lds),
        16, 0, 0);
}

#define DIM      2048
#define DSEQ     2048
#define DOUT     1024
#define NBATCH   8

// ---------- kernel 1: cast proj_w fp32 -> bf16 ----------
__global__ __launch_bounds__(256) void cast_w_kernel(const float* __restrict__ w,
                                                     unsigned short* __restrict__ o) {
    int i = (blockIdx.x * 256 + threadIdx.x) * 4;
    float4 v = *(const float4*)(w + i);
    unsigned int lo = (unsigned int)f2bf(v.x) | ((unsigned int)f2bf(v.y) << 16);
    unsigned int hi = (unsigned int)f2bf(v.z) | ((unsigned int)f2bf(v.w) << 16);
    *(uint2*)(o + i) = make_uint2(lo, hi);
}

// ---------- kernel 2: LayerNorm(gate) -> bf16, transposed to Gt[b][d][t] ----------
// block = 256 threads (4 waves), handles 32 consecutive t-rows of one batch.
__global__ __launch_bounds__(256) void ln_t_kernel(const float* __restrict__ X,
                                                   const float* __restrict__ lns,
                                                   const float* __restrict__ lnb,
                                                   unsigned short* __restrict__ Gt) {
    const int tid  = threadIdx.x;
    const int wave = tid >> 6;
    const int lane = tid & 63;
    const int t0   = blockIdx.x * 32;
    const int b    = blockIdx.y;

    __shared__ unsigned short lt[32][1028];   // pitch 1028 (8B-aligned rows, de-conflicted)

    #pragma unroll
    for (int i = 0; i < 8; ++i) {
        const int r = wave * 8 + i;
        const float* xr = X + ((size_t)(b * DSEQ + t0 + r)) * DIM + DOUT;  // gate half
        float4 v[4];
        float s = 0.f, ss = 0.f;
        #pragma unroll
        for (int c = 0; c < 4; ++c) {
            v[c] = *(const float4*)(xr + c * 256 + lane * 4);
            s  += v[c].x + v[c].y + v[c].z + v[c].w;
            ss += v[c].x * v[c].x + v[c].y * v[c].y + v[c].z * v[c].z + v[c].w * v[c].w;
        }
        #pragma unroll
        for (int off = 32; off > 0; off >>= 1) {
            s  += __shfl_xor(s,  off, 64);
            ss += __shfl_xor(ss, off, 64);
        }
        const float mu  = s * (1.f / 1024.f);
        const float var = ss * (1.f / 1024.f) - mu * mu;
        const float inv = rsqrtf(var + 1e-5f);
        #pragma unroll
        for (int c = 0; c < 4; ++c) {
            const int d = c * 256 + lane * 4;
            float4 sc = *(const float4*)(lns + d);
            float4 bi = *(const float4*)(lnb + d);
            float y0 = (v[c].x - mu) * inv * sc.x + bi.x;
            float y1 = (v[c].y - mu) * inv * sc.y + bi.y;
            float y2 = (v[c].z - mu) * inv * sc.z + bi.z;
            float y3 = (v[c].w - mu) * inv * sc.w + bi.w;
            unsigned int lo = (unsigned int)f2bf(y0) | ((unsigned int)f2bf(y1) << 16);
            unsigned int hi = (unsigned int)f2bf(y2) | ((unsigned int)f2bf(y3) << 16);
            *(uint2*)&lt[r][d] = make_uint2(lo, hi);
        }
    }
    __syncthreads();

    // transposed write-out: Gt[b][d][t0..t0+31], 64B per (thread,d)
    #pragma unroll
    for (int it = 0; it < 4; ++it) {
        const int d = it * 256 + tid;
        unsigned int u[16];
        #pragma unroll
        for (int j = 0; j < 16; ++j)
            u[j] = (unsigned int)lt[2 * j][d] | ((unsigned int)lt[2 * j + 1][d] << 16);
        uint4* dst = (uint4*)(Gt + ((size_t)(b * DOUT + d)) * DSEQ + t0);
        dst[0] = make_uint4(u[0],  u[1],  u[2],  u[3]);
        dst[1] = make_uint4(u[4],  u[5],  u[6],  u[7]);
        dst[2] = make_uint4(u[8],  u[9],  u[10], u[11]);
        dst[3] = make_uint4(u[12], u[13], u[14], u[15]);
    }
}

// ---------- kernel 3: bf16 MFMA GEMM + fused epilogue ----------
// out[b,s,d] = (sum_t W[s,t]*Gt[b,d,t] + proj_b[s]) * X[b,s,d(res half)]
#define BM 128
#define BN 128
#define BK 32

__global__ __launch_bounds__(256) void gemm_sgu(const unsigned short* __restrict__ Wb,
                                                const unsigned short* __restrict__ Gt,
                                                const float* __restrict__ X,
                                                const float* __restrict__ Pb,
                                                float* __restrict__ Out) {
    const int K   = DSEQ;
    const int tid = threadIdx.x;
    const int s0  = blockIdx.x * BM;
    const int d0  = blockIdx.y * BN;
    const int b   = blockIdx.z;

    __shared__ unsigned short As[BM * BK];  // 8 KB, linear [row][k] (global_load_lds: no pad)
    __shared__ unsigned short Bs[BN * BK];  // 8 KB

    const int wave = tid >> 6;
    const int lane = tid & 63;
    const int wr   = wave >> 1;   // 0..1 : 64-row group
    const int wc   = wave & 1;    // 0..1 : 64-col group
    const int ln15 = lane & 15;
    const int q    = lane >> 4;   // 0..3

    const int row = tid >> 2;          // staging row 0..63 (and +64)
    const int c8  = (tid & 3) * 8;     // staging k-chunk

    floatx4 acc[4][4] = {};

    const unsigned short* aG = Wb + (size_t)s0 * K;
    const unsigned short* bG = Gt + ((size_t)(b * DOUT + d0)) * K;

    for (int k0 = 0; k0 < K; k0 += BK) {
        __syncthreads();
        async16(&As[(size_t)row * BK + c8],        aG + (size_t)row * K        + k0 + c8);
        async16(&As[(size_t)(row + 64) * BK + c8], aG + (size_t)(row + 64) * K + k0 + c8);
        async16(&Bs[(size_t)row * BK + c8],        bG + (size_t)row * K        + k0 + c8);
        async16(&Bs[(size_t)(row + 64) * BK + c8], bG + (size_t)(row + 64) * K + k0 + c8);
        __syncthreads();

        short8 af[4], bf[4];
        #pragma unroll
        for (int i = 0; i < 4; ++i)
            af[i] = *(const short8*)&As[(wr * 64 + i * 16 + ln15) * BK + q * 8];
        #pragma unroll
        for (int i = 0; i < 4; ++i)
            bf[i] = *(const short8*)&Bs[(wc * 64 + i * 16 + ln15) * BK + q * 8];
        #pragma unroll
        for (int i = 0; i < 4; ++i)
            #pragma unroll
            for (int j = 0; j < 4; ++j)
                acc[i][j] = __builtin_amdgcn_mfma_f32_16x16x32_bf16(af[i], bf[j], acc[i][j], 0, 0, 0);
    }

    // epilogue: C/D layout col=lane&15, row=q*4+reg
    #pragma unroll
    for (int i = 0; i < 4; ++i) {
        const int srow = s0 + wr * 64 + i * 16 + q * 4;
        #pragma unroll
        for (int j = 0; j < 4; ++j) {
            const int d = d0 + wc * 64 + j * 16 + ln15;
            #pragma unroll
            for (int r = 0; r < 4; ++r) {
                const int s = srow + r;
                const float g = acc[i][j][r] + Pb[s];
                const size_t xi = ((size_t)(b * DSEQ + s)) * DIM + d;   // res half: d < 1024
                const size_t oi = ((size_t)(b * DSEQ + s)) * DOUT + d;
                Out[oi] = g * X[xi];
            }
        }
    }
}

// ---------- launcher ----------
extern "C" void kernel_launch(void* const* d_in, const int* in_sizes, int n_in,
                              void* d_out, int out_size, void* d_ws, size_t ws_size,
                              hipStream_t stream) {
    const float* x    = (const float*)d_in[0];
    const float* pw   = (const float*)d_in[1];
    const float* pb   = (const float*)d_in[2];
    const float* lns  = (const float*)d_in[3];
    const float* lnb  = (const float*)d_in[4];
    float* out        = (float*)d_out;

    unsigned short* Wb = (unsigned short*)d_ws;                                 // 8 MB
    unsigned short* Gt = (unsigned short*)((char*)d_ws + (size_t)DSEQ * DSEQ * 2); // 32 MB

    cast_w_kernel<<<dim3((DSEQ * DSEQ) / 1024), dim3(256), 0, stream>>>(pw, Wb);
    ln_t_kernel<<<dim3(DSEQ / 32, NBATCH), dim3(256), 0, stream>>>(x, lns, lnb, Gt);
    gemm_sgu<<<dim3(DSEQ / BM, DOUT / BN, NBATCH), dim3(256), 0, stream>>>(Wb, Gt, x, pb, out);
}

// Round 2
// 313.555 us; speedup vs baseline: 1.0354x; 1.0354x over previous
//
#include <hip/hip_runtime.h>

// ---------- helpers ----------
typedef __attribute__((ext_vector_type(8))) short short8;
typedef __attribute__((ext_vector_type(4))) float floatx4;

__device__ __forceinline__ unsigned short f2bf(float f) {
    unsigned int u = __builtin_bit_cast(unsigned int, f);
    u += 0x7fffu + ((u >> 16) & 1u);   // round-to-nearest-even (inputs are finite/normal)
    return (unsigned short)(u >> 16);
}

__device__ __forceinline__ void async16(unsigned short* lds, const unsigned short* g) {
    __builtin_amdgcn_global_load_lds(
        (__attribute__((address_space(1))) void*)(g),
        (__attribute__((address_space(3))) void*)(lds),
        16, 0, 0);
}

#define DIM      2048
#define DSEQ     2048
#define DOUT     1024
#define NBATCH   8
#define NKB      (DSEQ / 32)   // 64 k-slabs of width 32

// ---------- kernel 1: cast proj_w fp32 -> bf16, k-slab layout Wt[kb][s][32] ----------
__global__ __launch_bounds__(256) void cast_w_kernel(const float* __restrict__ w,
                                                     unsigned short* __restrict__ o) {
    int i = (blockIdx.x * 256 + threadIdx.x) * 4;
    int s = i >> 11;          // row (DSEQ=2048 wide)
    int t = i & 2047;         // 4 consecutive t within one 32-slab
    float4 v = *(const float4*)(w + i);
    unsigned int lo = (unsigned int)f2bf(v.x) | ((unsigned int)f2bf(v.y) << 16);
    unsigned int hi = (unsigned int)f2bf(v.z) | ((unsigned int)f2bf(v.w) << 16);
    unsigned short* dst = o + (((size_t)(t >> 5)) * DSEQ + s) * 32 + (t & 31);
    *(uint2*)dst = make_uint2(lo, hi);
}

// ---------- kernel 2: LayerNorm(gate) -> bf16, k-slab layout Gt[b][kb][d][32] ----------
// block = 256 threads (4 waves), handles 32 consecutive t-rows (= one slab) of one batch.
__global__ __launch_bounds__(256) void ln_t_kernel(const float* __restrict__ X,
                                                   const float* __restrict__ lns,
                                                   const float* __restrict__ lnb,
                                                   unsigned short* __restrict__ Gt) {
    const int tid  = threadIdx.x;
    const int wave = tid >> 6;
    const int lane = tid & 63;
    const int t0   = blockIdx.x * 32;
    const int b    = blockIdx.y;

    __shared__ unsigned short lt[32][1028];   // pitch 1028 (8B-aligned rows, de-conflicted)

    #pragma unroll
    for (int i = 0; i < 8; ++i) {
        const int r = wave * 8 + i;
        const float* xr = X + ((size_t)(b * DSEQ + t0 + r)) * DIM + DOUT;  // gate half
        float4 v[4];
        float s = 0.f, ss = 0.f;
        #pragma unroll
        for (int c = 0; c < 4; ++c) {
            v[c] = *(const float4*)(xr + c * 256 + lane * 4);
            s  += v[c].x + v[c].y + v[c].z + v[c].w;
            ss += v[c].x * v[c].x + v[c].y * v[c].y + v[c].z * v[c].z + v[c].w * v[c].w;
        }
        #pragma unroll
        for (int off = 32; off > 0; off >>= 1) {
            s  += __shfl_xor(s,  off, 64);
            ss += __shfl_xor(ss, off, 64);
        }
        const float mu  = s * (1.f / 1024.f);
        const float var = ss * (1.f / 1024.f) - mu * mu;
        const float inv = rsqrtf(var + 1e-5f);
        #pragma unroll
        for (int c = 0; c < 4; ++c) {
            const int d = c * 256 + lane * 4;
            float4 sc = *(const float4*)(lns + d);
            float4 bi = *(const float4*)(lnb + d);
            float y0 = (v[c].x - mu) * inv * sc.x + bi.x;
            float y1 = (v[c].y - mu) * inv * sc.y + bi.y;
            float y2 = (v[c].z - mu) * inv * sc.z + bi.z;
            float y3 = (v[c].w - mu) * inv * sc.w + bi.w;
            unsigned int lo = (unsigned int)f2bf(y0) | ((unsigned int)f2bf(y1) << 16);
            unsigned int hi = (unsigned int)f2bf(y2) | ((unsigned int)f2bf(y3) << 16);
            *(uint2*)&lt[r][d] = make_uint2(lo, hi);
        }
    }
    __syncthreads();

    // transposed write-out: Gt[b][t0/32][d][0..31] — 64B/thread, wave writes 4KB contiguous
    #pragma unroll
    for (int it = 0; it < 4; ++it) {
        const int d = it * 256 + tid;
        unsigned int u[16];
        #pragma unroll
        for (int j = 0; j < 16; ++j)
            u[j] = (unsigned int)lt[2 * j][d] | ((unsigned int)lt[2 * j + 1][d] << 16);
        uint4* dst = (uint4*)(Gt + (((size_t)b * NKB + (t0 >> 5)) * DOUT + d) * 32);
        dst[0] = make_uint4(u[0],  u[1],  u[2],  u[3]);
        dst[1] = make_uint4(u[4],  u[5],  u[6],  u[7]);
        dst[2] = make_uint4(u[8],  u[9],  u[10], u[11]);
        dst[3] = make_uint4(u[12], u[13], u[14], u[15]);
    }
}

// ---------- kernel 3: bf16 MFMA GEMM + fused epilogue ----------
// out[b,s,d] = (sum_t W[s,t]*G[b,t,d] + proj_b[s]) * X[b,s,d(res half)]
#define BM 128
#define BN 128
#define BK 64   // two 32-wide slabs per iteration

__global__ __launch_bounds__(256) void gemm_sgu(const unsigned short* __restrict__ Wt,
                                                const unsigned short* __restrict__ Gt,
                                                const float* __restrict__ X,
                                                const float* __restrict__ Pb,
                                                float* __restrict__ Out) {
    const int tid = threadIdx.x;
    const int s0  = blockIdx.x * BM;
    const int d0  = blockIdx.y * BN;
    const int b   = blockIdx.z;

    // two slab-halves each [128 rows][32 k] = 8KB; total 32KB
    __shared__ unsigned short As[2 * BM * 32];
    __shared__ unsigned short Bs[2 * BN * 32];

    const int wave = tid >> 6;
    const int lane = tid & 63;
    const int wr   = wave >> 1;   // 0..1 : 64-row group
    const int wc   = wave & 1;    // 0..1 : 64-col group
    const int ln15 = lane & 15;
    const int q    = lane >> 4;   // 0..3

    floatx4 acc[4][4] = {};

    for (int k0 = 0; k0 < DSEQ; k0 += BK) {
        const int kb = k0 >> 5;
        // slab bases: each an 8KB fully-contiguous block
        const unsigned short* aG = Wt + ((size_t)kb * DSEQ + s0) * 32;
        const unsigned short* bG = Gt + (((size_t)b * NKB + kb) * DOUT + d0) * 32;

        __syncthreads();
        // 32KB staging: 2048 chunks of 16B; 8 per thread, lane-linear
        #pragma unroll
        for (int j = 0; j < 2; ++j) {
            const int ch = tid + j * 256;           // 0..511 per 8KB region
            async16(&As[(size_t)ch * 8],        aG + (size_t)ch * 8);
            async16(&As[4096 + (size_t)ch * 8], aG + (size_t)DSEQ * 32 + (size_t)ch * 8);
            async16(&Bs[(size_t)ch * 8],        bG + (size_t)ch * 8);
            async16(&Bs[4096 + (size_t)ch * 8], bG + (size_t)DOUT * 32 + (size_t)ch * 8);
        }
        __syncthreads();

        #pragma unroll
        for (int u = 0; u < 2; ++u) {
            short8 af[4], bf[4];
            #pragma unroll
            for (int i = 0; i < 4; ++i)
                af[i] = *(const short8*)&As[(u * BM + wr * 64 + i * 16 + ln15) * 32 + q * 8];
            #pragma unroll
            for (int i = 0; i < 4; ++i)
                bf[i] = *(const short8*)&Bs[(u * BN + wc * 64 + i * 16 + ln15) * 32 + q * 8];
            #pragma unroll
            for (int i = 0; i < 4; ++i)
                #pragma unroll
                for (int j = 0; j < 4; ++j)
                    acc[i][j] = __builtin_amdgcn_mfma_f32_16x16x32_bf16(af[i], bf[j], acc[i][j], 0, 0, 0);
        }
    }

    // epilogue: C/D layout col=lane&15, row=q*4+reg
    #pragma unroll
    for (int i = 0; i < 4; ++i) {
        const int srow = s0 + wr * 64 + i * 16 + q * 4;
        #pragma unroll
        for (int j = 0; j < 4; ++j) {
            const int d = d0 + wc * 64 + j * 16 + ln15;
            #pragma unroll
            for (int r = 0; r < 4; ++r) {
                const int s = srow + r;
                const float g = acc[i][j][r] + Pb[s];
                const size_t xi = ((size_t)(b * DSEQ + s)) * DIM + d;   // res half: d < 1024
                const size_t oi = ((size_t)(b * DSEQ + s)) * DOUT + d;
                Out[oi] = g * X[xi];
            }
        }
    }
}

// ---------- launcher ----------
extern "C" void kernel_launch(void* const* d_in, const int* in_sizes, int n_in,
                              void* d_out, int out_size, void* d_ws, size_t ws_size,
                              hipStream_t stream) {
    const float* x    = (const float*)d_in[0];
    const float* pw   = (const float*)d_in[1];
    const float* pb   = (const float*)d_in[2];
    const float* lns  = (const float*)d_in[3];
    const float* lnb  = (const float*)d_in[4];
    float* out        = (float*)d_out;

    unsigned short* Wt = (unsigned short*)d_ws;                                    // 8 MB
    unsigned short* Gt = (unsigned short*)((char*)d_ws + (size_t)DSEQ * DSEQ * 2); // 32 MB

    cast_w_kernel<<<dim3((DSEQ * DSEQ) / 1024), dim3(256), 0, stream>>>(pw, Wt);
    ln_t_kernel<<<dim3(DSEQ / 32, NBATCH), dim3(256), 0, stream>>>(x, lns, lnb, Gt);
    gemm_sgu<<<dim3(DSEQ / BM, DOUT / BN, NBATCH), dim3(256), 0, stream>>>(Wt, Gt, x, pb, out);
}

// Round 3
// 311.593 us; speedup vs baseline: 1.0420x; 1.0063x over previous
//
#include <hip/hip_runtime.h>

// ---------- helpers ----------
typedef __attribute__((ext_vector_type(8))) short short8;
typedef __attribute__((ext_vector_type(4))) float floatx4;

__device__ __forceinline__ unsigned short f2bf(float f) {
    unsigned int u = __builtin_bit_cast(unsigned int, f);
    u += 0x7fffu + ((u >> 16) & 1u);   // round-to-nearest-even
    return (unsigned short)(u >> 16);
}

__device__ __forceinline__ void async16(unsigned short* lds, const unsigned short* g) {
    __builtin_amdgcn_global_load_lds(
        (__attribute__((address_space(1))) void*)(g),
        (__attribute__((address_space(3))) void*)(lds),
        16, 0, 0);
}

#define DIM      2048
#define DSEQ     2048
#define DOUT     1024
#define NBATCH   8
#define NKB      (DSEQ / 32)   // 64 k-slabs of width 32

// ---------- kernel 1: cast proj_w fp32 -> bf16, k-slab layout Wt[kb][s][32] ----------
__global__ __launch_bounds__(256) void cast_w_kernel(const float* __restrict__ w,
                                                     unsigned short* __restrict__ o) {
    int i = (blockIdx.x * 256 + threadIdx.x) * 4;
    int s = i >> 11;          // row (DSEQ=2048 wide)
    int t = i & 2047;         // 4 consecutive t within one 32-slab
    float4 v = *(const float4*)(w + i);
    unsigned int lo = (unsigned int)f2bf(v.x) | ((unsigned int)f2bf(v.y) << 16);
    unsigned int hi = (unsigned int)f2bf(v.z) | ((unsigned int)f2bf(v.w) << 16);
    unsigned short* dst = o + (((size_t)(t >> 5)) * DSEQ + s) * 32 + (t & 31);
    *(uint2*)dst = make_uint2(lo, hi);
}

// ---------- kernel 2: LayerNorm(gate) -> bf16, k-slab layout Gt[b][kb][d][32] ----------
__global__ __launch_bounds__(256) void ln_t_kernel(const float* __restrict__ X,
                                                   const float* __restrict__ lns,
                                                   const float* __restrict__ lnb,
                                                   unsigned short* __restrict__ Gt) {
    const int tid  = threadIdx.x;
    const int wave = tid >> 6;
    const int lane = tid & 63;
    const int t0   = blockIdx.x * 32;
    const int b    = blockIdx.y;

    __shared__ unsigned short lt[32][1028];   // pitch 1028 (8B-aligned rows)

    // hoisted row-invariant scale/bias (was reloaded 8x per thread)
    float4 sc[4], bi[4];
    #pragma unroll
    for (int c = 0; c < 4; ++c) {
        sc[c] = *(const float4*)(lns + c * 256 + lane * 4);
        bi[c] = *(const float4*)(lnb + c * 256 + lane * 4);
    }

    #pragma unroll 1   // cap register pressure: one row in flight per wave
    for (int i = 0; i < 8; ++i) {
        const int r = wave * 8 + i;
        const float* xr = X + ((size_t)(b * DSEQ + t0 + r)) * DIM + DOUT;  // gate half
        float4 v[4];
        float s = 0.f, ss = 0.f;
        #pragma unroll
        for (int c = 0; c < 4; ++c) {
            v[c] = *(const float4*)(xr + c * 256 + lane * 4);
            s  += v[c].x + v[c].y + v[c].z + v[c].w;
            ss += v[c].x * v[c].x + v[c].y * v[c].y + v[c].z * v[c].z + v[c].w * v[c].w;
        }
        #pragma unroll
        for (int off = 32; off > 0; off >>= 1) {
            s  += __shfl_xor(s,  off, 64);
            ss += __shfl_xor(ss, off, 64);
        }
        const float mu  = s * (1.f / 1024.f);
        const float var = ss * (1.f / 1024.f) - mu * mu;
        const float inv = rsqrtf(var + 1e-5f);
        #pragma unroll
        for (int c = 0; c < 4; ++c) {
            const int d = c * 256 + lane * 4;
            float y0 = (v[c].x - mu) * inv * sc[c].x + bi[c].x;
            float y1 = (v[c].y - mu) * inv * sc[c].y + bi[c].y;
            float y2 = (v[c].z - mu) * inv * sc[c].z + bi[c].z;
            float y3 = (v[c].w - mu) * inv * sc[c].w + bi[c].w;
            unsigned int lo = (unsigned int)f2bf(y0) | ((unsigned int)f2bf(y1) << 16);
            unsigned int hi = (unsigned int)f2bf(y2) | ((unsigned int)f2bf(y3) << 16);
            *(uint2*)&lt[r][d] = make_uint2(lo, hi);
        }
    }
    __syncthreads();

    // transposed write-out: Gt[b][t0/32][d][0..31] — wave writes 4KB contiguous
    #pragma unroll
    for (int it = 0; it < 4; ++it) {
        const int d = it * 256 + tid;
        unsigned int u[16];
        #pragma unroll
        for (int j = 0; j < 16; ++j)
            u[j] = (unsigned int)lt[2 * j][d] | ((unsigned int)lt[2 * j + 1][d] << 16);
        uint4* dst = (uint4*)(Gt + (((size_t)b * NKB + (t0 >> 5)) * DOUT + d) * 32);
        dst[0] = make_uint4(u[0],  u[1],  u[2],  u[3]);
        dst[1] = make_uint4(u[4],  u[5],  u[6],  u[7]);
        dst[2] = make_uint4(u[8],  u[9],  u[10], u[11]);
        dst[3] = make_uint4(u[12], u[13], u[14], u[15]);
    }
}

// ---------- kernel 3: bf16 MFMA GEMM + fused epilogue ----------
// out[b,s,d] = (sum_t W[s,t]*G[b,t,d] + proj_b[s]) * X[b,s,d(res half)]
// LDS: [row][64 k], XOR-swizzled chunks (chunk' = chunk ^ (row&7)) -> conflict-free b128 reads.
#define BM 128
#define BN 128
#define BK 64

__global__ __launch_bounds__(256) void gemm_sgu(const unsigned short* __restrict__ Wt,
                                                const unsigned short* __restrict__ Gt,
                                                const float* __restrict__ X,
                                                const float* __restrict__ Pb,
                                                float* __restrict__ Out) {
    const int tid = threadIdx.x;
    const int s0  = blockIdx.x * BM;
    const int d0  = blockIdx.y * BN;
    const int b   = blockIdx.z;

    __shared__ unsigned short As[BM * 64];   // 16 KB
    __shared__ unsigned short Bs[BN * 64];   // 16 KB

    const int wave = tid >> 6;
    const int lane = tid & 63;
    const int wr   = wave >> 1;
    const int wc   = wave & 1;
    const int ln15 = lane & 15;
    const int q    = lane >> 4;

    // ---- loop-invariant staging offsets ----
    // chunk c (16B) at LDS pos c holds source k-chunk (c&7)^(r&7) of row r=c>>3
    int ldsOff[4], srcA[4], srcB[4];
    #pragma unroll
    for (int j = 0; j < 4; ++j) {
        const int c   = tid + j * 256;
        const int r   = c >> 3;
        const int kc  = (c & 7) ^ (r & 7);
        const int u   = kc >> 2;      // which 32-slab
        const int cc  = kc & 3;       // 16B chunk within slab
        ldsOff[j] = c * 8;
        srcA[j]   = (u * DSEQ + s0 + r) * 32 + cc * 8;
        srcB[j]   = (u * DOUT + d0 + r) * 32 + cc * 8;
    }
    // ---- loop-invariant fragment offsets ----
    int aOff[2][4], bOff[2][4];
    #pragma unroll
    for (int u = 0; u < 2; ++u)
        #pragma unroll
        for (int i = 0; i < 4; ++i) {
            const int ra = wr * 64 + i * 16 + ln15;
            const int rb = wc * 64 + i * 16 + ln15;
            aOff[u][i] = ra * 64 + (((u * 4 + q) ^ (ra & 7)) * 8);
            bOff[u][i] = rb * 64 + (((u * 4 + q) ^ (rb & 7)) * 8);
        }

    floatx4 acc[4][4] = {};

    const unsigned short* gB = Gt + (size_t)b * NKB * DOUT * 32;

    for (int kb = 0; kb < NKB; kb += 2) {
        const unsigned short* aBase = Wt + (size_t)kb * DSEQ * 32;
        const unsigned short* bBase = gB + (size_t)kb * DOUT * 32;
        __syncthreads();
        #pragma unroll
        for (int j = 0; j < 4; ++j) {
            async16(&As[ldsOff[j]], aBase + srcA[j]);
            async16(&Bs[ldsOff[j]], bBase + srcB[j]);
        }
        __syncthreads();

        #pragma unroll
        for (int u = 0; u < 2; ++u) {
            short8 af[4], bf[4];
            #pragma unroll
            for (int i = 0; i < 4; ++i) af[i] = *(const short8*)&As[aOff[u][i]];
            #pragma unroll
            for (int i = 0; i < 4; ++i) bf[i] = *(const short8*)&Bs[bOff[u][i]];
            #pragma unroll
            for (int i = 0; i < 4; ++i)
                #pragma unroll
                for (int j = 0; j < 4; ++j)
                    acc[i][j] = __builtin_amdgcn_mfma_f32_16x16x32_bf16(af[i], bf[j], acc[i][j], 0, 0, 0);
        }
    }

    // epilogue: C/D layout col=lane&15, row=q*4+reg
    #pragma unroll
    for (int i = 0; i < 4; ++i) {
        const int srow = s0 + wr * 64 + i * 16 + q * 4;
        const float4 pb4 = *(const float4*)(Pb + srow);
        #pragma unroll
        for (int j = 0; j < 4; ++j) {
            const int d = d0 + wc * 64 + j * 16 + ln15;
            #pragma unroll
            for (int r = 0; r < 4; ++r) {
                const int s = srow + r;
                const float g = acc[i][j][r] + ((const float*)&pb4)[r];
                const size_t xi = ((size_t)(b * DSEQ + s)) * DIM + d;   // res half
                const size_t oi = ((size_t)(b * DSEQ + s)) * DOUT + d;
                Out[oi] = g * X[xi];
            }
        }
    }
}

// ---------- launcher ----------
extern "C" void kernel_launch(void* const* d_in, const int* in_sizes, int n_in,
                              void* d_out, int out_size, void* d_ws, size_t ws_size,
                              hipStream_t stream) {
    const float* x    = (const float*)d_in[0];
    const float* pw   = (const float*)d_in[1];
    const float* pb   = (const float*)d_in[2];
    const float* lns  = (const float*)d_in[3];
    const float* lnb  = (const float*)d_in[4];
    float* out        = (float*)d_out;

    unsigned short* Wt = (unsigned short*)d_ws;                                    // 8 MB
    unsigned short* Gt = (unsigned short*)((char*)d_ws + (size_t)DSEQ * DSEQ * 2); // 32 MB

    cast_w_kernel<<<dim3((DSEQ * DSEQ) / 1024), dim3(256), 0, stream>>>(pw, Wt);
    ln_t_kernel<<<dim3(DSEQ / 32, NBATCH), dim3(256), 0, stream>>>(x, lns, lnb, Gt);
    gemm_sgu<<<dim3(DSEQ / BM, DOUT / BN, NBATCH), dim3(256), 0, stream>>>(Wt, Gt, x, pb, out);
}

// Round 4
// 310.693 us; speedup vs baseline: 1.0450x; 1.0029x over previous
//
#include <hip/hip_runtime.h>

// ---------- helpers ----------
typedef __attribute__((ext_vector_type(8))) short short8;
typedef __attribute__((ext_vector_type(4))) float floatx4;

__device__ __forceinline__ unsigned short f2bf(float f) {
    unsigned int u = __builtin_bit_cast(unsigned int, f);
    u += 0x7fffu + ((u >> 16) & 1u);   // round-to-nearest-even
    return (unsigned short)(u >> 16);
}

__device__ __forceinline__ void async16(unsigned short* lds, const unsigned short* g) {
    __builtin_amdgcn_global_load_lds(
        (__attribute__((address_space(1))) void*)(g),
        (__attribute__((address_space(3))) void*)(lds),
        16, 0, 0);
}

#define DIM      2048
#define DSEQ     2048
#define DOUT     1024
#define NBATCH   8
#define NKB      (DSEQ / 32)   // 64 k-slabs of width 32

// ---------- kernel 1: cast proj_w fp32 -> bf16, k-slab layout Wt[kb][s][32] ----------
__global__ __launch_bounds__(256) void cast_w_kernel(const float* __restrict__ w,
                                                     unsigned short* __restrict__ o) {
    int i = (blockIdx.x * 256 + threadIdx.x) * 4;
    int s = i >> 11;
    int t = i & 2047;
    float4 v = *(const float4*)(w + i);
    unsigned int lo = (unsigned int)f2bf(v.x) | ((unsigned int)f2bf(v.y) << 16);
    unsigned int hi = (unsigned int)f2bf(v.z) | ((unsigned int)f2bf(v.w) << 16);
    unsigned short* dst = o + (((size_t)(t >> 5)) * DSEQ + s) * 32 + (t & 31);
    *(uint2*)dst = make_uint2(lo, hi);
}

// ---------- kernel 2: LayerNorm(gate) -> bf16, k-slab layout Gt[b][kb][d][32] ----------
__global__ __launch_bounds__(256) void ln_t_kernel(const float* __restrict__ X,
                                                   const float* __restrict__ lns,
                                                   const float* __restrict__ lnb,
                                                   unsigned short* __restrict__ Gt) {
    const int tid  = threadIdx.x;
    const int wave = tid >> 6;
    const int lane = tid & 63;
    const int t0   = blockIdx.x * 32;
    const int b    = blockIdx.y;

    __shared__ unsigned short lt[32][1028];

    float4 sc[4], bi[4];
    #pragma unroll
    for (int c = 0; c < 4; ++c) {
        sc[c] = *(const float4*)(lns + c * 256 + lane * 4);
        bi[c] = *(const float4*)(lnb + c * 256 + lane * 4);
    }

    #pragma unroll 1
    for (int i = 0; i < 8; ++i) {
        const int r = wave * 8 + i;
        const float* xr = X + ((size_t)(b * DSEQ + t0 + r)) * DIM + DOUT;
        float4 v[4];
        float s = 0.f, ss = 0.f;
        #pragma unroll
        for (int c = 0; c < 4; ++c) {
            v[c] = *(const float4*)(xr + c * 256 + lane * 4);
            s  += v[c].x + v[c].y + v[c].z + v[c].w;
            ss += v[c].x * v[c].x + v[c].y * v[c].y + v[c].z * v[c].z + v[c].w * v[c].w;
        }
        #pragma unroll
        for (int off = 32; off > 0; off >>= 1) {
            s  += __shfl_xor(s,  off, 64);
            ss += __shfl_xor(ss, off, 64);
        }
        const float mu  = s * (1.f / 1024.f);
        const float var = ss * (1.f / 1024.f) - mu * mu;
        const float inv = rsqrtf(var + 1e-5f);
        #pragma unroll
        for (int c = 0; c < 4; ++c) {
            const int d = c * 256 + lane * 4;
            float y0 = (v[c].x - mu) * inv * sc[c].x + bi[c].x;
            float y1 = (v[c].y - mu) * inv * sc[c].y + bi[c].y;
            float y2 = (v[c].z - mu) * inv * sc[c].z + bi[c].z;
            float y3 = (v[c].w - mu) * inv * sc[c].w + bi[c].w;
            unsigned int lo = (unsigned int)f2bf(y0) | ((unsigned int)f2bf(y1) << 16);
            unsigned int hi = (unsigned int)f2bf(y2) | ((unsigned int)f2bf(y3) << 16);
            *(uint2*)&lt[r][d] = make_uint2(lo, hi);
        }
    }
    __syncthreads();

    #pragma unroll
    for (int it = 0; it < 4; ++it) {
        const int d = it * 256 + tid;
        unsigned int u[16];
        #pragma unroll
        for (int j = 0; j < 16; ++j)
            u[j] = (unsigned int)lt[2 * j][d] | ((unsigned int)lt[2 * j + 1][d] << 16);
        uint4* dst = (uint4*)(Gt + (((size_t)b * NKB + (t0 >> 5)) * DOUT + d) * 32);
        dst[0] = make_uint4(u[0],  u[1],  u[2],  u[3]);
        dst[1] = make_uint4(u[4],  u[5],  u[6],  u[7]);
        dst[2] = make_uint4(u[8],  u[9],  u[10], u[11]);
        dst[3] = make_uint4(u[12], u[13], u[14], u[15]);
    }
}

// ---------- kernel 3: pipelined bf16 MFMA GEMM + vectorized fused epilogue ----------
// out[b,s,d] = (sum_t W[s,t]*G[b,t,d] + proj_b[s]) * X[b,s,d(res half)]
// BK=32, double-buffered LDS (2x16KB), ONE barrier per K-iter: prefetch tile k+1
// issues right after the barrier, MFMA of tile k overlaps the loads.
#define BM 128
#define BN 128

__global__ __launch_bounds__(256) void gemm_sgu(const unsigned short* __restrict__ Wt,
                                                const unsigned short* __restrict__ Gt,
                                                const float* __restrict__ X,
                                                const float* __restrict__ Pb,
                                                float* __restrict__ Out) {
    const int tid = threadIdx.x;
    const int s0  = blockIdx.x * BM;
    const int d0  = blockIdx.y * BN;
    const int b   = blockIdx.z;

    __shared__ __align__(16) unsigned char smem[32768];   // 2 x (As 8KB + Bs 8KB)

    const int wave = tid >> 6;
    const int lane = tid & 63;
    const int wr   = wave >> 1;
    const int wc   = wave & 1;
    const int ln15 = lane & 15;
    const int q    = lane >> 4;

    // staging offsets: chunk c (16B) of an 8KB buffer; row r=c>>2, swizzle kc=(c&3)^(r&3)
    int ldsOff[2], srcA[2], srcB[2];
    #pragma unroll
    for (int j = 0; j < 2; ++j) {
        const int c  = tid + j * 256;       // 0..511
        const int r  = c >> 2;
        const int kc = (c & 3) ^ (r & 3);
        ldsOff[j] = c * 8;                   // shorts
        srcA[j]   = (s0 + r) * 32 + kc * 8;  // within slab kb
        srcB[j]   = (d0 + r) * 32 + kc * 8;
    }
    // fragment offsets (swizzled): row ra, chunk q' = q ^ (ra&3)
    int aOff[4], bOff[4];
    #pragma unroll
    for (int i = 0; i < 4; ++i) {
        const int ra = wr * 64 + i * 16 + ln15;
        const int rb = wc * 64 + i * 16 + ln15;
        aOff[i] = ra * 32 + ((q ^ (ra & 3)) * 8);
        bOff[i] = rb * 32 + ((q ^ (rb & 3)) * 8);
    }

    floatx4 acc[4][4] = {};

    const unsigned short* gB = Gt + (size_t)b * NKB * DOUT * 32;

    // prefetch tile 0 into buffer 0
    {
        const unsigned short* aBase = Wt;
        const unsigned short* bBase = gB;
        unsigned short* As = (unsigned short*)(smem);
        unsigned short* Bs = (unsigned short*)(smem + 8192);
        #pragma unroll
        for (int j = 0; j < 2; ++j) {
            async16(&As[ldsOff[j]], aBase + srcA[j]);
            async16(&Bs[ldsOff[j]], bBase + srcB[j]);
        }
    }

    for (int kb = 0; kb < NKB; ++kb) {
        unsigned short* Asc = (unsigned short*)(smem + (kb & 1) * 16384);
        unsigned short* Bsc = Asc + 8192 / 2;
        __syncthreads();   // vmcnt(0) drain here = tile kb has landed (issued 1 iter ago)

        if (kb + 1 < NKB) {  // prefetch tile kb+1 into other buffer (reads of it drained above)
            const unsigned short* aBase = Wt + (size_t)(kb + 1) * DSEQ * 32;
            const unsigned short* bBase = gB + (size_t)(kb + 1) * DOUT * 32;
            unsigned short* Asn = (unsigned short*)(smem + ((kb + 1) & 1) * 16384);
            unsigned short* Bsn = Asn + 8192 / 2;
            #pragma unroll
            for (int j = 0; j < 2; ++j) {
                async16(&Asn[ldsOff[j]], aBase + srcA[j]);
                async16(&Bsn[ldsOff[j]], bBase + srcB[j]);
            }
        }

        short8 af[4], bf[4];
        #pragma unroll
        for (int i = 0; i < 4; ++i) af[i] = *(const short8*)&Asc[aOff[i]];
        #pragma unroll
        for (int i = 0; i < 4; ++i) bf[i] = *(const short8*)&Bsc[bOff[i]];
        #pragma unroll
        for (int i = 0; i < 4; ++i)
            #pragma unroll
            for (int j = 0; j < 4; ++j)
                acc[i][j] = __builtin_amdgcn_mfma_f32_16x16x32_bf16(af[i], bf[j], acc[i][j], 0, 0, 0);
    }

    // ---- vectorized epilogue: 4 rounds of 32 rows through LDS transpose ----
    // round e covers tile rows {e*16..e*16+15} and {64+e*16..64+e*16+15}
    float (*ep)[132] = (float (*)[132])smem;   // 32 x 132 floats = 16.5 KB, reuses tile LDS
    const int gr  = tid >> 3;       // 0..31
    const int seg = tid & 7;        // 0..7
    #pragma unroll
    for (int e = 0; e < 4; ++e) {
        __syncthreads();   // prev round reads done (and, for e=0, drains trailing state)
        #pragma unroll
        for (int j = 0; j < 4; ++j) {
            const int C = wc * 64 + j * 16 + ln15;
            #pragma unroll
            for (int r = 0; r < 4; ++r)
                ep[wr * 16 + q * 4 + r][C] = acc[e][j][r];
        }
        __syncthreads();
        const int s = s0 + (gr >> 4) * 64 + e * 16 + (gr & 15);
        const int d = d0 + seg * 16;
        const float pb = Pb[s];
        const float* xr = X + ((size_t)(b * DSEQ + s)) * DIM + d;
        float*       orow = Out + ((size_t)(b * DSEQ + s)) * DOUT + d;
        #pragma unroll
        for (int w = 0; w < 4; ++w) {
            float4 c = *(const float4*)&ep[gr][seg * 16 + w * 4];
            float4 x = *(const float4*)(xr + w * 4);
            float4 o;
            o.x = (c.x + pb) * x.x;
            o.y = (c.y + pb) * x.y;
            o.z = (c.z + pb) * x.z;
            o.w = (c.w + pb) * x.w;
            *(float4*)(orow + w * 4) = o;
        }
    }
}

// ---------- launcher ----------
extern "C" void kernel_launch(void* const* d_in, const int* in_sizes, int n_in,
                              void* d_out, int out_size, void* d_ws, size_t ws_size,
                              hipStream_t stream) {
    const float* x    = (const float*)d_in[0];
    const float* pw   = (const float*)d_in[1];
    const float* pb   = (const float*)d_in[2];
    const float* lns  = (const float*)d_in[3];
    const float* lnb  = (const float*)d_in[4];
    float* out        = (float*)d_out;

    unsigned short* Wt = (unsigned short*)d_ws;                                    // 8 MB
    unsigned short* Gt = (unsigned short*)((char*)d_ws + (size_t)DSEQ * DSEQ * 2); // 32 MB

    cast_w_kernel<<<dim3((DSEQ * DSEQ) / 1024), dim3(256), 0, stream>>>(pw, Wt);
    ln_t_kernel<<<dim3(DSEQ / 32, NBATCH), dim3(256), 0, stream>>>(x, lns, lnb, Gt);
    gemm_sgu<<<dim3(DSEQ / BM, DOUT / BN, NBATCH), dim3(256), 0, stream>>>(Wt, Gt, x, pb, out);
}